// Round 20
// baseline (4693.475 us; speedup 1.0000x reference)
//
#include <hip/hip_runtime.h>
#include <hip/hip_bf16.h>

// Problem constants (from reference): T=8192 steps, batch=1, H=21 hidden.
#define T_LEN 8192
#define HDIM  21
#define GDIM  84           // 4*H gate rows
#define NGRP  (T_LEN / 4)  // 2048 groups of 4 timesteps
#define GSTRIDE (GDIM * 4) // 336 floats per group block
#define CHUNK 16           // steps per fused superstep (4 groups)
#define NCHUNK (T_LEN / CHUNK) // 512

#define LOG2E      1.4426950408889634f
#define TWO_LOG2E  2.8853900817779268f

typedef float floatx2 __attribute__((ext_vector_type(2)));
typedef unsigned u32x2 __attribute__((ext_vector_type(2)));

// packed FMA: acc.{x,y} += w.{x,y} * h(low 32 bits of SGPR pair, both halves)
#define PKFMA(acc_, w_, h_)                                                \
    asm("v_pk_fma_f32 %0, %1, %2, %0 op_sel_hi:[1,0,1]"                    \
        : "+v"(acc_) : "v"(w_), "s"(h_))

__device__ __forceinline__ float rcp_fast(float x) {
    return __builtin_amdgcn_rcpf(x);     // v_rcp_f32, ~1ulp
}
__device__ __forceinline__ float exp2_fast(float x) {   // 2^x
    float r; asm("v_exp_f32 %0, %1" : "=v"(r) : "v"(x)); return r;
}
__device__ __forceinline__ float exp2n_fast(float x) {  // 2^(-x)
    float r; asm("v_exp_f32 %0, -%1" : "=v"(r) : "v"(x)); return r;
}
// inputs pre-scaled by log2(e): sigm2(x) == sigmoid(x/log2e)
__device__ __forceinline__ float sigm2(float x) {
    return rcp_fast(1.0f + exp2n_fast(x));   // x->+inf: 1 ; x->-inf: 0
}

// ---------------------------------------------------------------------------
// K1: parallel input projections, GROUPED output zxG[g][j][q] (coalesced).
// Rows pre-scaled by log2e; g-rows (2H..3H-1) additionally x2 (tanh fold).
// ---------------------------------------------------------------------------
__global__ void zx12_kernel(const float* __restrict__ src,
                            const float* __restrict__ Wih1, const float* __restrict__ b1,
                            const float* __restrict__ Wih2, const float* __restrict__ b2,
                            float* __restrict__ zxG1, float* __restrict__ zxG2)
{
    int n = blockIdx.x * blockDim.x + threadIdx.x;
    if (n >= T_LEN * GDIM) return;
    unsigned g = (unsigned)n / GSTRIDE;
    unsigned r = (unsigned)n - g * GSTRIDE;
    unsigned j = r >> 2;
    unsigned t = (g << 2) | (r & 3);
    float4 s = *reinterpret_cast<const float4*>(src + 4 * t);
    float z1 = b1[j];
    z1 = __builtin_fmaf(Wih1[j * 3 + 0], s.x, z1);
    z1 = __builtin_fmaf(Wih1[j * 3 + 1], s.z, z1);
    z1 = __builtin_fmaf(Wih1[j * 3 + 2], s.w, z1);
    float z2 = b2[j];
    z2 = __builtin_fmaf(Wih2[j * 3 + 0], s.y, z2);
    z2 = __builtin_fmaf(Wih2[j * 3 + 1], s.z, z2);
    z2 = __builtin_fmaf(Wih2[j * 3 + 2], s.w, z2);
    float sc = (j >= 2 * HDIM && j < 3 * HDIM) ? TWO_LOG2E : LOG2E;
    zxG1[n] = z1 * sc;
    zxG2[n] = z2 * sc;
}

// ---------------------------------------------------------------------------
// K2: fold linear layers into LSTM3's input projection (unscaled).
// ---------------------------------------------------------------------------
__global__ void fold_kernel(const float* __restrict__ Wih3,
                            const float* __restrict__ W1, const float* __restrict__ bl1,
                            const float* __restrict__ W2, const float* __restrict__ bl2,
                            const float* __restrict__ b3,
                            float* __restrict__ M1, float* __restrict__ M2,
                            float* __restrict__ b3p)
{
    int idx = blockIdx.x * blockDim.x + threadIdx.x;
    if (idx < GDIM * HDIM) {
        int j = idx / HDIM, k = idx - j * HDIM;
        M1[idx] = Wih3[j * 50 + 0] * W1[k];
        float s = 0.0f;
        for (int m = 0; m < 49; ++m)
            s = __builtin_fmaf(Wih3[j * 50 + 1 + m], W2[m * HDIM + k], s);
        M2[idx] = s;
    }
    if (idx < GDIM) {
        float s = b3[idx] + Wih3[idx * 50 + 0] * bl1[0];
        for (int m = 0; m < 49; ++m)
            s = __builtin_fmaf(Wih3[idx * 50 + 1 + m], bl2[m], s);
        b3p[idx] = s;
    }
}

// ---------------------------------------------------------------------------
// K3: 4-wave, 3-stage pipelined fused scan (one wave per SIMD):
//   wave0 = LSTM1 gates -> h1 to hbuf        (chunk i)
//   wave1 = LSTM2 gates -> h2 to hbuf        (chunk i)
//   wave2 = projection M1*h1 + M2*h2 -> part (chunk i-1; feed-forward)
//   wave3 = LSTM3 from part -> h3out         (chunk i-2)
// Critical waves (0/1) no longer carry the 21 proj PKFMAs (+LDS write):
// ~61 instr/step instead of ~86. One barrier per 16 steps.
// ---------------------------------------------------------------------------
#define RLI(h_, l_) __builtin_amdgcn_readlane(__float_as_int(h_), 32 + (l_))
#define RLL(v_, l_) (long)(unsigned)__builtin_amdgcn_readlane(__float_as_int(v_), (l_))

#define BCAST_H(h_)                                                        \
    hsL_0  = (unsigned)RLI(h_, 0);  hsL_1  = (unsigned)RLI(h_, 1);         \
    hsL_2  = (unsigned)RLI(h_, 2);  hsL_3  = (unsigned)RLI(h_, 3);         \
    hsL_4  = (unsigned)RLI(h_, 4);  hsL_5  = (unsigned)RLI(h_, 5);         \
    hsL_6  = (unsigned)RLI(h_, 6);  hsL_7  = (unsigned)RLI(h_, 7);         \
    hsL_8  = (unsigned)RLI(h_, 8);  hsL_9  = (unsigned)RLI(h_, 9);         \
    hsL_10 = (unsigned)RLI(h_, 10); hsL_11 = (unsigned)RLI(h_, 11);        \
    hsL_12 = (unsigned)RLI(h_, 12); hsL_13 = (unsigned)RLI(h_, 13);        \
    hsL_14 = (unsigned)RLI(h_, 14); hsL_15 = (unsigned)RLI(h_, 15);        \
    hsL_16 = (unsigned)RLI(h_, 16); hsL_17 = (unsigned)RLI(h_, 17);        \
    hsL_18 = (unsigned)RLI(h_, 18); hsL_19 = (unsigned)RLI(h_, 19);        \
    hsL_20 = (unsigned)RLI(h_, 20);

// broadcast 21 h values from lanes base..base+20 of VGPR v_ into hL_*
#define BCAST_ANY(v_, b_)                                                  \
    hL_0  = RLL(v_, (b_) + 0);  hL_1  = RLL(v_, (b_) + 1);                 \
    hL_2  = RLL(v_, (b_) + 2);  hL_3  = RLL(v_, (b_) + 3);                 \
    hL_4  = RLL(v_, (b_) + 4);  hL_5  = RLL(v_, (b_) + 5);                 \
    hL_6  = RLL(v_, (b_) + 6);  hL_7  = RLL(v_, (b_) + 7);                 \
    hL_8  = RLL(v_, (b_) + 8);  hL_9  = RLL(v_, (b_) + 9);                 \
    hL_10 = RLL(v_, (b_) + 10); hL_11 = RLL(v_, (b_) + 11);                \
    hL_12 = RLL(v_, (b_) + 12); hL_13 = RLL(v_, (b_) + 13);                \
    hL_14 = RLL(v_, (b_) + 14); hL_15 = RLL(v_, (b_) + 15);                \
    hL_16 = RLL(v_, (b_) + 16); hL_17 = RLL(v_, (b_) + 17);                \
    hL_18 = RLL(v_, (b_) + 18); hL_19 = RLL(v_, (b_) + 19);                \
    hL_20 = RLL(v_, (b_) + 20);

// gates from zA_,zB_ (log2e-scaled, g-rows pre-doubled); updates c; hW; bcast
#define STEP_CORE(zA_, zB_)                                                \
        floatx2 q0, q1, q2;                                                \
        q0.x = (zA_); q0.y = (zB_);                                        \
        q1 = (floatx2)0.0f; q2 = (floatx2)0.0f;                            \
        PKFMA(q0, wab_0,  hsL_0);                                          \
        PKFMA(q1, wab_7,  hsL_7);                                          \
        PKFMA(q2, wab_14, hsL_14);                                         \
        PKFMA(q0, wab_1,  hsL_1);                                          \
        PKFMA(q1, wab_8,  hsL_8);                                          \
        PKFMA(q2, wab_15, hsL_15);                                         \
        PKFMA(q0, wab_2,  hsL_2);                                          \
        PKFMA(q1, wab_9,  hsL_9);                                          \
        PKFMA(q2, wab_16, hsL_16);                                         \
        PKFMA(q0, wab_3,  hsL_3);                                          \
        PKFMA(q1, wab_10, hsL_10);                                         \
        PKFMA(q2, wab_17, hsL_17);                                         \
        PKFMA(q0, wab_4,  hsL_4);                                          \
        PKFMA(q1, wab_11, hsL_11);                                         \
        PKFMA(q2, wab_18, hsL_18);                                         \
        PKFMA(q0, wab_5,  hsL_5);                                          \
        PKFMA(q1, wab_12, hsL_12);                                         \
        PKFMA(q2, wab_19, hsL_19);                                         \
        PKFMA(q0, wab_6,  hsL_6);                                          \
        PKFMA(q1, wab_13, hsL_13);                                         \
        PKFMA(q2, wab_20, hsL_20);                                         \
        floatx2 qt = (q0 + q1) + q2;                                       \
        float accA = qt.x;                                                 \
        float accB = qt.y;                                                 \
        float vA = sigm2(accA);                                            \
        float vB = __builtin_fmaf(mBc, sigm2(accB), aB);                   \
        float p_  = vA * vB;                                               \
        u32x2 rs_ = __builtin_amdgcn_permlane32_swap(                      \
            __float_as_uint(p_), __float_as_uint(p_), false, false);       \
        float pSw = (__uint_as_float(rs_.x) + __uint_as_float(rs_.y)) - p_;\
        c = __builtin_fmaf(vA, c, pSw);                                    \
        float th_ = __builtin_fmaf(                                        \
            -2.0f, rcp_fast(exp2_fast(TWO_LOG2E * c) + 1.0f), 1.0f);       \
        float hW  = vB * th_;                                              \
        BCAST_H(hW)

// waves 0/1: one step; write h (21 floats) to hbuf slot for the proj wave
#define W01_STEP(s_, zA_, zB_)                                             \
    {                                                                      \
        STEP_CORE(zA_, zB_)                                                \
        if (hi && act) hb[(s_) * HDIM + kk] = hW;                          \
    }

// wave2 (proj): one 21-term packed matvec pass, result to dst
#define PROJ_PASS(mp_, init_, dst_, s_)                                    \
    {                                                                      \
        floatx2 r0 = (init_), r1 = (floatx2)0.0f, r2 = (floatx2)0.0f;      \
        PKFMA(r0, mp_##0,  hL_0);                                          \
        PKFMA(r1, mp_##7,  hL_7);                                          \
        PKFMA(r2, mp_##14, hL_14);                                         \
        PKFMA(r0, mp_##1,  hL_1);                                          \
        PKFMA(r1, mp_##8,  hL_8);                                          \
        PKFMA(r2, mp_##15, hL_15);                                         \
        PKFMA(r0, mp_##2,  hL_2);                                          \
        PKFMA(r1, mp_##9,  hL_9);                                          \
        PKFMA(r2, mp_##16, hL_16);                                         \
        PKFMA(r0, mp_##3,  hL_3);                                          \
        PKFMA(r1, mp_##10, hL_10);                                         \
        PKFMA(r2, mp_##17, hL_17);                                         \
        PKFMA(r0, mp_##4,  hL_4);                                          \
        PKFMA(r1, mp_##11, hL_11);                                         \
        PKFMA(r2, mp_##18, hL_18);                                         \
        PKFMA(r0, mp_##5,  hL_5);                                          \
        PKFMA(r1, mp_##12, hL_12);                                         \
        PKFMA(r2, mp_##19, hL_19);                                         \
        PKFMA(r0, mp_##6,  hL_6);                                          \
        PKFMA(r1, mp_##13, hL_13);                                         \
        PKFMA(r2, mp_##20, hL_20);                                         \
        if (act) (dst_)[(s_) * 42 + slot] = (r0 + r1) + r2;                \
    }

// wave3: one LSTM3 step from part partials (bias pre-folded in LSTM1 pass)
#define W3_STEP(s_)                                                        \
    {                                                                      \
        floatx2 pz = pp0[(s_) * 42 + slot] + pp1[(s_) * 42 + slot];        \
        STEP_CORE(pz.x, pz.y)                                              \
        if (hi && act) h3out[(tbase + (s_)) * HDIM + k] = hW;              \
    }

#define LDG4(p_) (*reinterpret_cast<const float4*>(p_))

__global__ __launch_bounds__(256, 1)
void fused_scan_kernel(const float* __restrict__ zxG1, const float* __restrict__ Whh1,
                       const float* __restrict__ M1,
                       const float* __restrict__ zxG2, const float* __restrict__ Whh2,
                       const float* __restrict__ M2,
                       const float* __restrict__ Whh3, const float* __restrict__ b3p,
                       float* __restrict__ h3out)
{
    __shared__ floatx2 part[2][2][CHUNK][42];   // [lstm][buf][step][slot] 21.5KB
    __shared__ float   hbuf[2][2][CHUNK][HDIM]; // [lstm][buf][step][k]     5.4KB

    const int wid  = threadIdx.x >> 6;   // 0..3
    const int lane = threadIdx.x & 63;
    const int k = lane & 31;
    const bool hi = lane >= 32;
    const bool act = k < HDIM;
    const int kk = act ? k : 0;
    const int slot = kk + (hi ? HDIM : 0);   // 8B lane stride -> 2-bank/lane

    const int rowA = hi ? (HDIM + kk)     : kk;              // f : i  (sigmoid)
    const int rowB = hi ? (3 * HDIM + kk) : (2 * HDIM + kk); // o : g
    const float mBc = hi ? 1.0f : 2.0f;  // lo: tanh = 2*sigm2(2x)-1 (2x folded)
    const float aB  = hi ? 0.0f : -1.0f;
    const float scB = hi ? LOG2E : TWO_LOG2E;  // g-row doubling fold

    // gate weights for waves 0/1/3 (wave2 loads proj weights instead)
    const float* Whh = (wid == 0) ? Whh1 : (wid == 1) ? Whh2 : Whh3;
    const float* zxG = (wid == 1) ? zxG2 : zxG1;   // used by wid<2 only

    floatx2 wab_0,  wab_1,  wab_2,  wab_3,  wab_4,  wab_5,  wab_6;
    floatx2 wab_7,  wab_8,  wab_9,  wab_10, wab_11, wab_12, wab_13;
    floatx2 wab_14, wab_15, wab_16, wab_17, wab_18, wab_19, wab_20;
    floatx2 m1ab_0, m1ab_1, m1ab_2, m1ab_3, m1ab_4, m1ab_5, m1ab_6;
    floatx2 m1ab_7, m1ab_8, m1ab_9, m1ab_10, m1ab_11, m1ab_12, m1ab_13;
    floatx2 m1ab_14, m1ab_15, m1ab_16, m1ab_17, m1ab_18, m1ab_19, m1ab_20;
    floatx2 m2ab_0, m2ab_1, m2ab_2, m2ab_3, m2ab_4, m2ab_5, m2ab_6;
    floatx2 m2ab_7, m2ab_8, m2ab_9, m2ab_10, m2ab_11, m2ab_12, m2ab_13;
    floatx2 m2ab_14, m2ab_15, m2ab_16, m2ab_17, m2ab_18, m2ab_19, m2ab_20;
    floatx2 rb3;   // b3p fold (proj wave, LSTM1 pass init)

    if (wid != 2) {
        const float* WA = Whh + rowA * HDIM;
        const float* WB = Whh + rowB * HDIM;
#define LOADW(j_) wab_##j_.x = WA[j_] * LOG2E; wab_##j_.y = WB[j_] * scB;
        LOADW(0)  LOADW(1)  LOADW(2)  LOADW(3)  LOADW(4)  LOADW(5)  LOADW(6)
        LOADW(7)  LOADW(8)  LOADW(9)  LOADW(10) LOADW(11) LOADW(12) LOADW(13)
        LOADW(14) LOADW(15) LOADW(16) LOADW(17) LOADW(18) LOADW(19) LOADW(20)
#undef LOADW
    } else {
        const float* MA1 = M1 + rowA * HDIM;
        const float* MB1 = M1 + rowB * HDIM;
        const float* MA2 = M2 + rowA * HDIM;
        const float* MB2 = M2 + rowB * HDIM;
#define LOADM(j_)                                                          \
        m1ab_##j_.x = MA1[j_] * LOG2E; m1ab_##j_.y = MB1[j_] * scB;        \
        m2ab_##j_.x = MA2[j_] * LOG2E; m2ab_##j_.y = MB2[j_] * scB;
        LOADM(0)  LOADM(1)  LOADM(2)  LOADM(3)  LOADM(4)  LOADM(5)  LOADM(6)
        LOADM(7)  LOADM(8)  LOADM(9)  LOADM(10) LOADM(11) LOADM(12) LOADM(13)
        LOADM(14) LOADM(15) LOADM(16) LOADM(17) LOADM(18) LOADM(19) LOADM(20)
#undef LOADM
        rb3.x = b3p[rowA] * LOG2E;
        rb3.y = b3p[rowB] * scB;
    }

    // recurrence state (waves 0/1/3)
    long hsL_0 = 0, hsL_1 = 0, hsL_2 = 0, hsL_3 = 0, hsL_4 = 0, hsL_5 = 0;
    long hsL_6 = 0, hsL_7 = 0, hsL_8 = 0, hsL_9 = 0, hsL_10 = 0, hsL_11 = 0;
    long hsL_12 = 0, hsL_13 = 0, hsL_14 = 0, hsL_15 = 0, hsL_16 = 0;
    long hsL_17 = 0, hsL_18 = 0, hsL_19 = 0, hsL_20 = 0;
    float c = 0.0f;

    // zx chunk registers (waves 0/1): current chunk = 4 groups x 2 rows
    const float* baseA = zxG + rowA * 4;
    const float* baseB = zxG + rowB * 4;
    float4 cA0, cA1, cA2, cA3, cB0, cB1, cB2, cB3;
    if (wid < 2) {
        cA0 = LDG4(baseA + 0 * GSTRIDE); cA1 = LDG4(baseA + 1 * GSTRIDE);
        cA2 = LDG4(baseA + 2 * GSTRIDE); cA3 = LDG4(baseA + 3 * GSTRIDE);
        cB0 = LDG4(baseB + 0 * GSTRIDE); cB1 = LDG4(baseB + 1 * GSTRIDE);
        cB2 = LDG4(baseB + 2 * GSTRIDE); cB3 = LDG4(baseB + 3 * GSTRIDE);
    }

#pragma unroll 1
    for (int i = 0; i <= NCHUNK + 1; ++i) {
        if (wid < 2) {
            // prefetch next chunk (clamped; waits land a chunk later)
            float4 nA0, nA1, nA2, nA3, nB0, nB1, nB2, nB3;
            const int gn = (i + 1 < NCHUNK) ? (i + 1) : (NCHUNK - 1);
            const float* pA = baseA + (size_t)gn * 4 * GSTRIDE;
            const float* pB = baseB + (size_t)gn * 4 * GSTRIDE;
            nA0 = LDG4(pA + 0 * GSTRIDE); nA1 = LDG4(pA + 1 * GSTRIDE);
            nA2 = LDG4(pA + 2 * GSTRIDE); nA3 = LDG4(pA + 3 * GSTRIDE);
            nB0 = LDG4(pB + 0 * GSTRIDE); nB1 = LDG4(pB + 1 * GSTRIDE);
            nB2 = LDG4(pB + 2 * GSTRIDE); nB3 = LDG4(pB + 3 * GSTRIDE);

            if (i < NCHUNK) {
                float* hb = &hbuf[wid][i & 1][0][0];
                W01_STEP(0,  cA0.x, cB0.x) W01_STEP(1,  cA0.y, cB0.y)
                W01_STEP(2,  cA0.z, cB0.z) W01_STEP(3,  cA0.w, cB0.w)
                W01_STEP(4,  cA1.x, cB1.x) W01_STEP(5,  cA1.y, cB1.y)
                W01_STEP(6,  cA1.z, cB1.z) W01_STEP(7,  cA1.w, cB1.w)
                W01_STEP(8,  cA2.x, cB2.x) W01_STEP(9,  cA2.y, cB2.y)
                W01_STEP(10, cA2.z, cB2.z) W01_STEP(11, cA2.w, cB2.w)
                W01_STEP(12, cA3.x, cB3.x) W01_STEP(13, cA3.y, cB3.y)
                W01_STEP(14, cA3.z, cB3.z) W01_STEP(15, cA3.w, cB3.w)
            }
            cA0 = nA0; cA1 = nA1; cA2 = nA2; cA3 = nA3;
            cB0 = nB0; cB1 = nB1; cB2 = nB2; cB3 = nB3;
        } else if (wid == 2) {
            // proj wave: chunk i-1 (feed-forward, no cross-step dependence)
            if (i >= 1 && i <= NCHUNK) {
                const int buf = (i - 1) & 1;
                const float* hsrc = hi ? &hbuf[1][buf][0][0]
                                       : &hbuf[0][buf][0][0];
                floatx2* d0 = &part[0][buf][0][0];
                floatx2* d1 = &part[1][buf][0][0];
#pragma unroll 1
                for (int s = 0; s < CHUNK; ++s) {
                    // lane k<21 holds h1[k]; lane 32+k holds h2[k]
                    float hv = hsrc[s * HDIM + kk];
                    long hL_0, hL_1, hL_2, hL_3, hL_4, hL_5, hL_6, hL_7;
                    long hL_8, hL_9, hL_10, hL_11, hL_12, hL_13, hL_14;
                    long hL_15, hL_16, hL_17, hL_18, hL_19, hL_20;
                    BCAST_ANY(hv, 0)            // h1 from lanes 0..20
                    PROJ_PASS(m1ab_, rb3, d0, s)
                    BCAST_ANY(hv, 32)           // h2 from lanes 32..52
                    PROJ_PASS(m2ab_, (floatx2)0.0f, d1, s)
                }
            }
        } else {
            // wave3 = LSTM3: chunk i-2
            if (i >= 2) {
                const int buf = (i - 2) & 1;
                const int tbase = (i - 2) * CHUNK;
                const floatx2* pp0 = &part[0][buf][0][0];
                const floatx2* pp1 = &part[1][buf][0][0];
                W3_STEP(0)  W3_STEP(1)  W3_STEP(2)  W3_STEP(3)
                W3_STEP(4)  W3_STEP(5)  W3_STEP(6)  W3_STEP(7)
                W3_STEP(8)  W3_STEP(9)  W3_STEP(10) W3_STEP(11)
                W3_STEP(12) W3_STEP(13) W3_STEP(14) W3_STEP(15)
            }
        }
        __syncthreads();
    }
}

// ---------------------------------------------------------------------------
// K4: final linear: out[t] = h3[t] @ W3.T + bl3   (W3: [2,21])
// ---------------------------------------------------------------------------
__global__ void out_kernel(const float* __restrict__ h3, const float* __restrict__ W3,
                           const float* __restrict__ bl3, float* __restrict__ out)
{
    int t = blockIdx.x * blockDim.x + threadIdx.x;
    if (t >= T_LEN) return;
    float s0 = bl3[0], s1 = bl3[1];
#pragma unroll
    for (int kq = 0; kq < HDIM; ++kq) {
        float h = h3[t * HDIM + kq];
        s0 = __builtin_fmaf(W3[kq], h, s0);
        s1 = __builtin_fmaf(W3[HDIM + kq], h, s1);
    }
    out[t * 2 + 0] = s0;
    out[t * 2 + 1] = s1;
}

extern "C" void kernel_launch(void* const* d_in, const int* in_sizes, int n_in,
                              void* d_out, int out_size, void* d_ws, size_t ws_size,
                              hipStream_t stream) {
    const float* src  = (const float*)d_in[0];
    const float* Wih1 = (const float*)d_in[1];
    const float* Whh1 = (const float*)d_in[2];
    const float* b1   = (const float*)d_in[3];
    const float* W1   = (const float*)d_in[4];
    const float* bl1  = (const float*)d_in[5];
    const float* Wih2 = (const float*)d_in[6];
    const float* Whh2 = (const float*)d_in[7];
    const float* b2   = (const float*)d_in[8];
    const float* W2   = (const float*)d_in[9];
    const float* bl2  = (const float*)d_in[10];
    const float* Wih3 = (const float*)d_in[11];
    const float* Whh3 = (const float*)d_in[12];
    const float* b3   = (const float*)d_in[13];
    const float* W3   = (const float*)d_in[14];
    const float* bl3  = (const float*)d_in[15];
    float* out = (float*)d_out;

    float* ws   = (float*)d_ws;
    float* zxG1 = ws;
    float* zxG2 = zxG1 + (size_t)T_LEN * GDIM;
    float* h3   = zxG2 + (size_t)T_LEN * GDIM;
    float* M1   = h3   + (size_t)T_LEN * HDIM;
    float* M2   = M1   + GDIM * HDIM;
    float* b3p  = M2   + GDIM * HDIM;

    zx12_kernel<<<(T_LEN * GDIM + 255) / 256, 256, 0, stream>>>(
        src, Wih1, b1, Wih2, b2, zxG1, zxG2);
    fold_kernel<<<(GDIM * HDIM + 255) / 256, 256, 0, stream>>>(
        Wih3, W1, bl1, W2, bl2, b3, M1, M2, b3p);
    fused_scan_kernel<<<1, 256, 0, stream>>>(
        zxG1, Whh1, M1, zxG2, Whh2, M2, Whh3, b3p, h3);
    out_kernel<<<(T_LEN + 255) / 256, 256, 0, stream>>>(h3, W3, bl3, out);
}

// Round 21
// 1967.922 us; speedup vs baseline: 2.3850x; 2.3850x over previous
//
#include <hip/hip_runtime.h>
#include <hip/hip_bf16.h>

// Problem constants (from reference): T=8192 steps, batch=1, H=21 hidden.
#define T_LEN 8192
#define HDIM  21
#define GDIM  84           // 4*H gate rows
#define NGRP  (T_LEN / 4)  // 2048 groups of 4 timesteps
#define GSTRIDE (GDIM * 4) // 336 floats per group block
#define CHUNK 16           // steps per fused superstep (4 groups)
#define NCHUNK (T_LEN / CHUNK) // 512

#define LOG2E      1.4426950408889634f
#define TWO_LOG2E  2.8853900817779268f

typedef float floatx2 __attribute__((ext_vector_type(2)));
typedef unsigned u32x2 __attribute__((ext_vector_type(2)));

// packed FMA: acc.{x,y} += w.{x,y} * hs(low 32 bits of SGPR pair, both halves)
#define PKFMA(acc_, w_, h_)                                                \
    asm("v_pk_fma_f32 %0, %1, %2, %0 op_sel_hi:[1,0,1]"                    \
        : "+v"(acc_) : "v"(w_), "s"(h_))

__device__ __forceinline__ float rcp_fast(float x) {
    return __builtin_amdgcn_rcpf(x);     // v_rcp_f32, ~1ulp
}
__device__ __forceinline__ float exp2_fast(float x) {   // 2^x
    float r; asm("v_exp_f32 %0, %1" : "=v"(r) : "v"(x)); return r;
}
__device__ __forceinline__ float exp2n_fast(float x) {  // 2^(-x)
    float r; asm("v_exp_f32 %0, -%1" : "=v"(r) : "v"(x)); return r;
}
// inputs pre-scaled by log2(e): sigm2(x) == sigmoid(x/log2e)
__device__ __forceinline__ float sigm2(float x) {
    return rcp_fast(1.0f + exp2n_fast(x));   // x->+inf: 1 ; x->-inf: 0
}

// ---------------------------------------------------------------------------
// K1: parallel input projections, GROUPED output zxG[g][j][q] (coalesced).
// Rows pre-scaled by log2e; g-rows (2H..3H-1) additionally x2 (tanh fold).
// ---------------------------------------------------------------------------
__global__ void zx12_kernel(const float* __restrict__ src,
                            const float* __restrict__ Wih1, const float* __restrict__ b1,
                            const float* __restrict__ Wih2, const float* __restrict__ b2,
                            float* __restrict__ zxG1, float* __restrict__ zxG2)
{
    int n = blockIdx.x * blockDim.x + threadIdx.x;
    if (n >= T_LEN * GDIM) return;
    unsigned g = (unsigned)n / GSTRIDE;
    unsigned r = (unsigned)n - g * GSTRIDE;
    unsigned j = r >> 2;
    unsigned t = (g << 2) | (r & 3);
    float4 s = *reinterpret_cast<const float4*>(src + 4 * t);
    float z1 = b1[j];
    z1 = __builtin_fmaf(Wih1[j * 3 + 0], s.x, z1);
    z1 = __builtin_fmaf(Wih1[j * 3 + 1], s.z, z1);
    z1 = __builtin_fmaf(Wih1[j * 3 + 2], s.w, z1);
    float z2 = b2[j];
    z2 = __builtin_fmaf(Wih2[j * 3 + 0], s.y, z2);
    z2 = __builtin_fmaf(Wih2[j * 3 + 1], s.z, z2);
    z2 = __builtin_fmaf(Wih2[j * 3 + 2], s.w, z2);
    float sc = (j >= 2 * HDIM && j < 3 * HDIM) ? TWO_LOG2E : LOG2E;
    zxG1[n] = z1 * sc;
    zxG2[n] = z2 * sc;
}

// ---------------------------------------------------------------------------
// K2: fold linear layers into LSTM3's input projection (unscaled).
// ---------------------------------------------------------------------------
__global__ void fold_kernel(const float* __restrict__ Wih3,
                            const float* __restrict__ W1, const float* __restrict__ bl1,
                            const float* __restrict__ W2, const float* __restrict__ bl2,
                            const float* __restrict__ b3,
                            float* __restrict__ M1, float* __restrict__ M2,
                            float* __restrict__ b3p)
{
    int idx = blockIdx.x * blockDim.x + threadIdx.x;
    if (idx < GDIM * HDIM) {
        int j = idx / HDIM, k = idx - j * HDIM;
        M1[idx] = Wih3[j * 50 + 0] * W1[k];
        float s = 0.0f;
        for (int m = 0; m < 49; ++m)
            s = __builtin_fmaf(Wih3[j * 50 + 1 + m], W2[m * HDIM + k], s);
        M2[idx] = s;
    }
    if (idx < GDIM) {
        float s = b3[idx] + Wih3[idx * 50 + 0] * bl1[0];
        for (int m = 0; m < 49; ++m)
            s = __builtin_fmaf(Wih3[idx * 50 + 1 + m], bl2[m], s);
        b3p[idx] = s;
    }
}

// ---------------------------------------------------------------------------
// K3: CHUNKED fused 3-LSTM scan (R19 champion structure, restored).
//   wave0 = LSTM1, wave1 = LSTM2 (+ M*h projection into LDS, pk-paired)
//   wave2 = LSTM3, one chunk behind.
// CHUNK=16 (32 regressed: VGPR/I-cache), slot map kk + 21*hi (2-bank/lane),
// proj on the h-producing wave (4-wave split regressed: readlane chain).
// ---------------------------------------------------------------------------
#define RLI(h_, l_) __builtin_amdgcn_readlane(__float_as_int(h_), 32 + (l_))

#define BCAST_H(h_)                                                        \
    hsL_0  = (unsigned)RLI(h_, 0);  hsL_1  = (unsigned)RLI(h_, 1);         \
    hsL_2  = (unsigned)RLI(h_, 2);  hsL_3  = (unsigned)RLI(h_, 3);         \
    hsL_4  = (unsigned)RLI(h_, 4);  hsL_5  = (unsigned)RLI(h_, 5);         \
    hsL_6  = (unsigned)RLI(h_, 6);  hsL_7  = (unsigned)RLI(h_, 7);         \
    hsL_8  = (unsigned)RLI(h_, 8);  hsL_9  = (unsigned)RLI(h_, 9);         \
    hsL_10 = (unsigned)RLI(h_, 10); hsL_11 = (unsigned)RLI(h_, 11);        \
    hsL_12 = (unsigned)RLI(h_, 12); hsL_13 = (unsigned)RLI(h_, 13);        \
    hsL_14 = (unsigned)RLI(h_, 14); hsL_15 = (unsigned)RLI(h_, 15);        \
    hsL_16 = (unsigned)RLI(h_, 16); hsL_17 = (unsigned)RLI(h_, 17);        \
    hsL_18 = (unsigned)RLI(h_, 18); hsL_19 = (unsigned)RLI(h_, 19);        \
    hsL_20 = (unsigned)RLI(h_, 20);

// gates from zA_,zB_ (log2e-scaled, g-rows pre-doubled); updates c; hW; bcast
#define STEP_CORE(zA_, zB_)                                                \
        floatx2 q0, q1, q2;                                                \
        q0.x = (zA_); q0.y = (zB_);                                        \
        q1 = (floatx2)0.0f; q2 = (floatx2)0.0f;                            \
        PKFMA(q0, wab_0,  hsL_0);                                          \
        PKFMA(q1, wab_7,  hsL_7);                                          \
        PKFMA(q2, wab_14, hsL_14);                                         \
        PKFMA(q0, wab_1,  hsL_1);                                          \
        PKFMA(q1, wab_8,  hsL_8);                                          \
        PKFMA(q2, wab_15, hsL_15);                                         \
        PKFMA(q0, wab_2,  hsL_2);                                          \
        PKFMA(q1, wab_9,  hsL_9);                                          \
        PKFMA(q2, wab_16, hsL_16);                                         \
        PKFMA(q0, wab_3,  hsL_3);                                          \
        PKFMA(q1, wab_10, hsL_10);                                         \
        PKFMA(q2, wab_17, hsL_17);                                         \
        PKFMA(q0, wab_4,  hsL_4);                                          \
        PKFMA(q1, wab_11, hsL_11);                                         \
        PKFMA(q2, wab_18, hsL_18);                                         \
        PKFMA(q0, wab_5,  hsL_5);                                          \
        PKFMA(q1, wab_12, hsL_12);                                         \
        PKFMA(q2, wab_19, hsL_19);                                         \
        PKFMA(q0, wab_6,  hsL_6);                                          \
        PKFMA(q1, wab_13, hsL_13);                                         \
        PKFMA(q2, wab_20, hsL_20);                                         \
        floatx2 qt = (q0 + q1) + q2;                                       \
        float accA = qt.x;                                                 \
        float accB = qt.y;                                                 \
        float vA = sigm2(accA);                                            \
        float vB = __builtin_fmaf(mBc, sigm2(accB), aB);                   \
        float p_  = vA * vB;                                               \
        u32x2 rs_ = __builtin_amdgcn_permlane32_swap(                      \
            __float_as_uint(p_), __float_as_uint(p_), false, false);       \
        float pSw = (__uint_as_float(rs_.x) + __uint_as_float(rs_.y)) - p_;\
        c = __builtin_fmaf(vA, c, pSw);                                    \
        float th_ = __builtin_fmaf(                                        \
            -2.0f, rcp_fast(exp2_fast(TWO_LOG2E * c) + 1.0f), 1.0f);       \
        float hW  = vB * th_;                                              \
        BCAST_H(hW)

// waves 0/1: one step + packed folded projection into LDS at slot_
#define W01_STEP(s_, zA_, zB_)                                             \
    {                                                                      \
        STEP_CORE(zA_, zB_)                                                \
        floatx2 r0 = rbias, r1 = (floatx2)0.0f, r2 = (floatx2)0.0f;        \
        PKFMA(r0, mab_0,  hsL_0);                                          \
        PKFMA(r1, mab_7,  hsL_7);                                          \
        PKFMA(r2, mab_14, hsL_14);                                         \
        PKFMA(r0, mab_1,  hsL_1);                                          \
        PKFMA(r1, mab_8,  hsL_8);                                          \
        PKFMA(r2, mab_15, hsL_15);                                         \
        PKFMA(r0, mab_2,  hsL_2);                                          \
        PKFMA(r1, mab_9,  hsL_9);                                          \
        PKFMA(r2, mab_16, hsL_16);                                         \
        PKFMA(r0, mab_3,  hsL_3);                                          \
        PKFMA(r1, mab_10, hsL_10);                                         \
        PKFMA(r2, mab_17, hsL_17);                                         \
        PKFMA(r0, mab_4,  hsL_4);                                          \
        PKFMA(r1, mab_11, hsL_11);                                         \
        PKFMA(r2, mab_18, hsL_18);                                         \
        PKFMA(r0, mab_5,  hsL_5);                                          \
        PKFMA(r1, mab_12, hsL_12);                                         \
        PKFMA(r2, mab_19, hsL_19);                                         \
        PKFMA(r0, mab_6,  hsL_6);                                          \
        PKFMA(r1, mab_13, hsL_13);                                         \
        PKFMA(r2, mab_20, hsL_20);                                         \
        if (act) pp[(s_) * 42 + slot] = (r0 + r1) + r2;                    \
    }

// wave2: one LSTM3 step from LDS partials at slot (bias pre-folded by wave0)
#define W2_STEP(s_)                                                        \
    {                                                                      \
        floatx2 pz = pp0[(s_) * 42 + slot] + pp1[(s_) * 42 + slot];        \
        STEP_CORE(pz.x, pz.y)                                              \
        if (hi && act) h3out[(tbase + (s_)) * HDIM + k] = hW;              \
    }

#define LDG4(p_) (*reinterpret_cast<const float4*>(p_))

__global__ __launch_bounds__(192, 1)
void fused_scan_kernel(const float* __restrict__ zxG1, const float* __restrict__ Whh1,
                       const float* __restrict__ M1,
                       const float* __restrict__ zxG2, const float* __restrict__ Whh2,
                       const float* __restrict__ M2,
                       const float* __restrict__ Whh3, const float* __restrict__ b3p,
                       float* __restrict__ h3out)
{
    __shared__ floatx2 part[2][2][CHUNK][42];   // [lstm][buf][step][slot] = 21.5KB

    const int wid  = threadIdx.x >> 6;   // 0,1,2
    const int lane = threadIdx.x & 63;
    const int k = lane & 31;
    const bool hi = lane >= 32;
    const bool act = k < HDIM;
    const int kk = act ? k : 0;
    const int slot = kk + (hi ? HDIM : 0);   // 8B lane stride -> 2-bank/lane

    const int rowA = hi ? (HDIM + kk)     : kk;              // f : i  (sigmoid)
    const int rowB = hi ? (3 * HDIM + kk) : (2 * HDIM + kk); // o : g
    const float mBc = hi ? 1.0f : 2.0f;  // lo: tanh = 2*sigm2(2x)-1 (2x folded)
    const float aB  = hi ? 0.0f : -1.0f;
    const float scB = hi ? LOG2E : TWO_LOG2E;  // g-row doubling fold

    const float* Whh = (wid == 0) ? Whh1 : (wid == 1) ? Whh2 : Whh3;
    const float* zxG = (wid == 1) ? zxG2 : zxG1;                 // dummy for wid2
    const float* Mm  = (wid == 0) ? M1 : (wid == 1) ? M2 : Whh3; // dummy for wid2

    const float* WA = Whh + rowA * HDIM;
    const float* WB = Whh + rowB * HDIM;
    const float* MA = Mm  + rowA * HDIM;
    const float* MB = Mm  + rowB * HDIM;

    // recurrent weights packed (wa_j, wb_j), pre-scaled (g-rows x2)
    floatx2 wab_0,  wab_1,  wab_2,  wab_3,  wab_4,  wab_5,  wab_6;
    floatx2 wab_7,  wab_8,  wab_9,  wab_10, wab_11, wab_12, wab_13;
    floatx2 wab_14, wab_15, wab_16, wab_17, wab_18, wab_19, wab_20;
#define LOADW(j_) wab_##j_.x = WA[j_] * LOG2E; wab_##j_.y = WB[j_] * scB;
    LOADW(0)  LOADW(1)  LOADW(2)  LOADW(3)  LOADW(4)  LOADW(5)  LOADW(6)
    LOADW(7)  LOADW(8)  LOADW(9)  LOADW(10) LOADW(11) LOADW(12) LOADW(13)
    LOADW(14) LOADW(15) LOADW(16) LOADW(17) LOADW(18) LOADW(19) LOADW(20)
#undef LOADW

    // projection weights packed (ma_j, mb_j), pre-scaled (g-rows x2)
    floatx2 mab_0,  mab_1,  mab_2,  mab_3,  mab_4,  mab_5,  mab_6;
    floatx2 mab_7,  mab_8,  mab_9,  mab_10, mab_11, mab_12, mab_13;
    floatx2 mab_14, mab_15, mab_16, mab_17, mab_18, mab_19, mab_20;
#define LOADM(j_) mab_##j_.x = MA[j_] * LOG2E; mab_##j_.y = MB[j_] * scB;
    LOADM(0)  LOADM(1)  LOADM(2)  LOADM(3)  LOADM(4)  LOADM(5)  LOADM(6)
    LOADM(7)  LOADM(8)  LOADM(9)  LOADM(10) LOADM(11) LOADM(12) LOADM(13)
    LOADM(14) LOADM(15) LOADM(16) LOADM(17) LOADM(18) LOADM(19) LOADM(20)
#undef LOADM

    // LSTM3 bias folded into wave0's proj accumulator init (wave1 adds 0)
    floatx2 rbias;
    rbias.x = (wid == 0) ? b3p[rowA] * LOG2E : 0.0f;
    rbias.y = (wid == 0) ? b3p[rowB] * scB   : 0.0f;

    // h state as SGPR pairs (low word = hs bits) + cell state
    long hsL_0 = 0, hsL_1 = 0, hsL_2 = 0, hsL_3 = 0, hsL_4 = 0, hsL_5 = 0;
    long hsL_6 = 0, hsL_7 = 0, hsL_8 = 0, hsL_9 = 0, hsL_10 = 0, hsL_11 = 0;
    long hsL_12 = 0, hsL_13 = 0, hsL_14 = 0, hsL_15 = 0, hsL_16 = 0;
    long hsL_17 = 0, hsL_18 = 0, hsL_19 = 0, hsL_20 = 0;
    float c = 0.0f;

    // zx chunk registers (waves 0/1): current chunk = 4 groups x 2 rows
    const float* baseA = zxG + rowA * 4;
    const float* baseB = zxG + rowB * 4;
    float4 cA0, cA1, cA2, cA3, cB0, cB1, cB2, cB3;
    if (wid < 2) {
        cA0 = LDG4(baseA + 0 * GSTRIDE); cA1 = LDG4(baseA + 1 * GSTRIDE);
        cA2 = LDG4(baseA + 2 * GSTRIDE); cA3 = LDG4(baseA + 3 * GSTRIDE);
        cB0 = LDG4(baseB + 0 * GSTRIDE); cB1 = LDG4(baseB + 1 * GSTRIDE);
        cB2 = LDG4(baseB + 2 * GSTRIDE); cB3 = LDG4(baseB + 3 * GSTRIDE);
    }

#pragma unroll 1
    for (int i = 0; i <= NCHUNK; ++i) {
        // prefetch next chunk (clamped in-bounds; waits land a full chunk later)
        float4 nA0, nA1, nA2, nA3, nB0, nB1, nB2, nB3;
        if (wid < 2) {
            const int gn = (i + 1 < NCHUNK) ? (i + 1) : (NCHUNK - 1);
            const float* pA = baseA + (size_t)gn * 4 * GSTRIDE;
            const float* pB = baseB + (size_t)gn * 4 * GSTRIDE;
            nA0 = LDG4(pA + 0 * GSTRIDE); nA1 = LDG4(pA + 1 * GSTRIDE);
            nA2 = LDG4(pA + 2 * GSTRIDE); nA3 = LDG4(pA + 3 * GSTRIDE);
            nB0 = LDG4(pB + 0 * GSTRIDE); nB1 = LDG4(pB + 1 * GSTRIDE);
            nB2 = LDG4(pB + 2 * GSTRIDE); nB3 = LDG4(pB + 3 * GSTRIDE);

            if (i < NCHUNK) {
                floatx2* pp = &part[wid][i & 1][0][0];
                W01_STEP(0,  cA0.x, cB0.x) W01_STEP(1,  cA0.y, cB0.y)
                W01_STEP(2,  cA0.z, cB0.z) W01_STEP(3,  cA0.w, cB0.w)
                W01_STEP(4,  cA1.x, cB1.x) W01_STEP(5,  cA1.y, cB1.y)
                W01_STEP(6,  cA1.z, cB1.z) W01_STEP(7,  cA1.w, cB1.w)
                W01_STEP(8,  cA2.x, cB2.x) W01_STEP(9,  cA2.y, cB2.y)
                W01_STEP(10, cA2.z, cB2.z) W01_STEP(11, cA2.w, cB2.w)
                W01_STEP(12, cA3.x, cB3.x) W01_STEP(13, cA3.y, cB3.y)
                W01_STEP(14, cA3.z, cB3.z) W01_STEP(15, cA3.w, cB3.w)
            }
        } else if (i >= 1) {
            const int buf = (i - 1) & 1;
            const int tbase = (i - 1) * CHUNK;
            const floatx2* pp0 = &part[0][buf][0][0];
            const floatx2* pp1 = &part[1][buf][0][0];
            W2_STEP(0)  W2_STEP(1)  W2_STEP(2)  W2_STEP(3)
            W2_STEP(4)  W2_STEP(5)  W2_STEP(6)  W2_STEP(7)
            W2_STEP(8)  W2_STEP(9)  W2_STEP(10) W2_STEP(11)
            W2_STEP(12) W2_STEP(13) W2_STEP(14) W2_STEP(15)
        }
        __syncthreads();
        if (wid < 2) {
            cA0 = nA0; cA1 = nA1; cA2 = nA2; cA3 = nA3;
            cB0 = nB0; cB1 = nB1; cB2 = nB2; cB3 = nB3;
        }
    }
}

// ---------------------------------------------------------------------------
// K4: final linear: out[t] = h3[t] @ W3.T + bl3   (W3: [2,21])
// ---------------------------------------------------------------------------
__global__ void out_kernel(const float* __restrict__ h3, const float* __restrict__ W3,
                           const float* __restrict__ bl3, float* __restrict__ out)
{
    int t = blockIdx.x * blockDim.x + threadIdx.x;
    if (t >= T_LEN) return;
    float s0 = bl3[0], s1 = bl3[1];
#pragma unroll
    for (int kq = 0; kq < HDIM; ++kq) {
        float h = h3[t * HDIM + kq];
        s0 = __builtin_fmaf(W3[kq], h, s0);
        s1 = __builtin_fmaf(W3[HDIM + kq], h, s1);
    }
    out[t * 2 + 0] = s0;
    out[t * 2 + 1] = s1;
}

extern "C" void kernel_launch(void* const* d_in, const int* in_sizes, int n_in,
                              void* d_out, int out_size, void* d_ws, size_t ws_size,
                              hipStream_t stream) {
    const float* src  = (const float*)d_in[0];
    const float* Wih1 = (const float*)d_in[1];
    const float* Whh1 = (const float*)d_in[2];
    const float* b1   = (const float*)d_in[3];
    const float* W1   = (const float*)d_in[4];
    const float* bl1  = (const float*)d_in[5];
    const float* Wih2 = (const float*)d_in[6];
    const float* Whh2 = (const float*)d_in[7];
    const float* b2   = (const float*)d_in[8];
    const float* W2   = (const float*)d_in[9];
    const float* bl2  = (const float*)d_in[10];
    const float* Wih3 = (const float*)d_in[11];
    const float* Whh3 = (const float*)d_in[12];
    const float* b3   = (const float*)d_in[13];
    const float* W3   = (const float*)d_in[14];
    const float* bl3  = (const float*)d_in[15];
    float* out = (float*)d_out;

    float* ws   = (float*)d_ws;
    float* zxG1 = ws;
    float* zxG2 = zxG1 + (size_t)T_LEN * GDIM;
    float* h3   = zxG2 + (size_t)T_LEN * GDIM;
    float* M1   = h3   + (size_t)T_LEN * HDIM;
    float* M2   = M1   + GDIM * HDIM;
    float* b3p  = M2   + GDIM * HDIM;

    zx12_kernel<<<(T_LEN * GDIM + 255) / 256, 256, 0, stream>>>(
        src, Wih1, b1, Wih2, b2, zxG1, zxG2);
    fold_kernel<<<(GDIM * HDIM + 255) / 256, 256, 0, stream>>>(
        Wih3, W1, bl1, W2, bl2, b3, M1, M2, b3p);
    fused_scan_kernel<<<1, 192, 0, stream>>>(
        zxG1, Whh1, M1, zxG2, Whh2, M2, Whh3, b3p, h3);
    out_kernel<<<(T_LEN + 255) / 256, 256, 0, stream>>>(h3, W3, bl3, out);
}